// Round 4
// baseline (258.568 us; speedup 1.0000x reference)
//
#include <hip/hip_runtime.h>
#include <hip/hip_bf16.h>
#include <math.h>

// Problem constants (from reference)
constexpr int kN2 = 180224, kN1 = 11264, kN0 = 1024;
constexpr int kE1 = 168960, kE2 = 10240;
constexpr int kIN = 602, kHID = 256, kOUT = 41;
constexpr int kKP = 608;  // kIN padded to multiple of 32 (MFMA K)

typedef __attribute__((ext_vector_type(8))) short bf16x8;
typedef __attribute__((ext_vector_type(4))) float f32x4;

static __device__ __forceinline__ ushort f2bf(float v) {
    return __bfloat16_as_ushort(__float2bfloat16(v));
}

// ---------------------------------------------------------------------------
// Generic CSR build: histogram -> single-block scan -> bucket scatter.
// ---------------------------------------------------------------------------
__global__ __launch_bounds__(256)
void hist_kernel(const int* __restrict__ dst, int* __restrict__ cnt, int nE) {
    const int e = blockIdx.x * 256 + threadIdx.x;
    if (e < nE) atomicAdd(&cnt[dst[e]], 1);
}

__global__ __launch_bounds__(256)
void scan_kernel(const int* __restrict__ cnt, int* __restrict__ off, int nN) {
    __shared__ int part[256];
    const int t = threadIdx.x;
    const int CH = nN / 256;
    const int base = t * CH;
    int s = 0;
    for (int i = 0; i < CH; ++i) s += cnt[base + i];
    part[t] = s;
    __syncthreads();
    for (int ofs = 1; ofs < 256; ofs <<= 1) {
        int v = (t >= ofs) ? part[t - ofs] : 0;
        __syncthreads();
        if (t >= ofs) part[t] += v;
        __syncthreads();
    }
    int run = (t == 0) ? 0 : part[t - 1];
    for (int i = 0; i < CH; ++i) {
        off[base + i] = run;
        run += cnt[base + i];
    }
    if (t == 255) off[nN] = run;
}

__global__ __launch_bounds__(256)
void bucket_kernel(const int* __restrict__ src, const int* __restrict__ dst,
                   const int* __restrict__ off, int* __restrict__ cur,
                   int* __restrict__ ebuf, int nE) {
    const int e = blockIdx.x * 256 + threadIdx.x;
    if (e < nE) {
        const int d = dst[e];
        const int p = atomicAdd(&cur[d], 1);
        ebuf[off[d] + p] = src[e];
    }
}

// ---------------------------------------------------------------------------
// Aggregation layer 1: block per dst node, float2 loads (rows are 8B-aligned:
// 602 floats = 301 float2 exactly), fp32 accumulate, packed-uint bf16 mean
// stores into the padded [kN1][608] GEMM operand buffer.
// ---------------------------------------------------------------------------
__global__ __launch_bounds__(128)
void aggregate1_kernel(const float* __restrict__ x, const int* __restrict__ off,
                       const int* __restrict__ ebuf, ushort* __restrict__ aggb) {
    const int d = blockIdx.x;
    const int t = threadIdx.x;
    const int b = off[d], e = off[d + 1];
    float a0x = 0.f, a0y = 0.f, a1x = 0.f, a1y = 0.f, a2x = 0.f, a2y = 0.f;
    int s_next = (b < e) ? ebuf[b] : 0;
    for (int i = b; i < e; ++i) {
        const int s = s_next;
        if (i + 1 < e) s_next = ebuf[i + 1];
        const float2* row = (const float2*)(x + (size_t)s * kIN);
        const float2 r0 = row[t];
        const float2 r1 = row[t + 128];
        a0x += r0.x; a0y += r0.y;
        a1x += r1.x; a1y += r1.y;
        if (t < 45) {
            const float2 r2 = row[t + 256];
            a2x += r2.x; a2y += r2.y;
        }
    }
    const float inv = 1.0f / fmaxf((float)(e - b), 1.0f);
    uint* ar = (uint*)(aggb + (size_t)d * kKP);  // 304 uints per row
    ar[t]       = (uint)f2bf(a0x * inv) | ((uint)f2bf(a0y * inv) << 16);
    ar[t + 128] = (uint)f2bf(a1x * inv) | ((uint)f2bf(a1y * inv) << 16);
    if (t < 45) ar[t + 256] = (uint)f2bf(a2x * inv) | ((uint)f2bf(a2y * inv) << 16);
    if (t >= 45 && t < 48) ar[t + 256] = 0u;  // zero pad shorts 602..607
}

// ---------------------------------------------------------------------------
// Convert x[:N1] fp32 [kN1][602] -> bf16 [kN1][608]; flat uint-task grid,
// stores perfectly coalesced.
// ---------------------------------------------------------------------------
__global__ __launch_bounds__(256)
void conv_x1_kernel(const float* __restrict__ x, ushort* __restrict__ xb) {
    const int task = blockIdx.x * 256 + threadIdx.x;  // row*304 + u
    const int row = task / 304;
    const int u = task - row * 304;
    uint v = 0u;
    if (u < 301) {
        const float2 f = *(const float2*)(x + (size_t)row * kIN + 2 * u);
        v = (uint)f2bf(f.x) | ((uint)f2bf(f.y) << 16);
    }
    ((uint*)xb)[task] = v;
}

// Convert+transpose W [602][256] -> Wt bf16 [256][608] (zero-padded K tail).
__global__ __launch_bounds__(256)
void conv_w_kernel(const float* __restrict__ W, ushort* __restrict__ Wt) {
    const int j = blockIdx.x;
    for (int k = threadIdx.x; k < kKP; k += 256) {
        float v = (k < kIN) ? W[(size_t)k * kHID + j] : 0.f;
        Wt[(size_t)j * kKP + k] = f2bf(v);
    }
}

// ---------------------------------------------------------------------------
// Layer-1 GEMM via MFMA: h = relu(agg @ W1l + b1 + x @ W1r).
// 64x128 block tile, 4 waves, K-step 32. Double-buffered LDS staged with
// global_load_lds width=16 (linear dest, inverse-swizzled SOURCE, swizzled
// READ -- rule #21). Chunk layout: 16B chunk c = [A: p*256+r*4+slot |
// B: 512+p*512+rb*4+slot], slot = k8 ^ ((row>>1)&3) -> frag ds_read_b128 is
// 2-way (free). One __syncthreads per K-step drains next-tile stage.
// ---------------------------------------------------------------------------
constexpr int kNT = kKP / 32;  // 19 K-steps

__global__ __launch_bounds__(256)
void layer1_mfma(const ushort* __restrict__ aggb, const ushort* __restrict__ xb,
                 const ushort* __restrict__ wlt, const ushort* __restrict__ wrt,
                 const float* __restrict__ b1, float* __restrict__ h) {
    __shared__ ushort buf[2][1536 * 8];  // 2 x 24KB
    const int t = threadIdx.x;
    const int lane = t & 63, wid = t >> 6;
    const int bid = blockIdx.x;
    const int n0 = (bid >> 1) * 64;
    const int j0 = (bid & 1) * 128;

    f32x4 acc[4][2];
#pragma unroll
    for (int m = 0; m < 4; ++m)
#pragma unroll
        for (int n = 0; n < 2; ++n) acc[m][n] = (f32x4){0.f, 0.f, 0.f, 0.f};

    // stage K-step kt into buf[db]: 1536 16B chunks, 24 wave-stripes of 64
    auto stage = [&](int kt, int db) {
        const int k0 = kt * 32;
#pragma unroll
        for (int i = 0; i < 6; ++i) {
            const int stripe = i * 4 + wid;
            const int c = stripe * 64 + lane;
            const ushort* g;
            if (c < 512) {
                const int mat = c >> 8, r = (c >> 2) & 63, slot = c & 3;
                const int k8 = slot ^ ((r >> 1) & 3);
                g = (mat ? xb : aggb) + (size_t)(n0 + r) * kKP + k0 + k8 * 8;
            } else {
                const int c2 = c - 512;
                const int mat = c2 >> 9, rb = (c2 >> 2) & 127, slot = c2 & 3;
                const int k8 = slot ^ ((rb >> 1) & 3);
                g = (mat ? wrt : wlt) + (size_t)(j0 + rb) * kKP + k0 + k8 * 8;
            }
            __builtin_amdgcn_global_load_lds(
                (const __attribute__((address_space(1))) void*)g,
                (__attribute__((address_space(3))) void*)&buf[db][stripe * 512],
                16, 0, 0);
        }
    };

    stage(0, 0);
    __syncthreads();

    const int rl = lane & 15;
    const int k8 = lane >> 4;
    int db = 0;
    for (int kt = 0; kt < kNT; ++kt) {
        if (kt + 1 < kNT) stage(kt + 1, db ^ 1);

        bf16x8 af[4][2], bfr[2][2];
#pragma unroll
        for (int m = 0; m < 4; ++m)
#pragma unroll
            for (int p = 0; p < 2; ++p) {
                const int r = m * 16 + rl;
                const int slot = k8 ^ ((r >> 1) & 3);
                const int c = p * 256 + r * 4 + slot;
                af[m][p] = *(const bf16x8*)&buf[db][c * 8];
            }
#pragma unroll
        for (int n = 0; n < 2; ++n)
#pragma unroll
            for (int p = 0; p < 2; ++p) {
                const int rb = wid * 32 + n * 16 + rl;
                const int slot = k8 ^ ((rb >> 1) & 3);
                const int c = 512 + p * 512 + rb * 4 + slot;
                bfr[n][p] = *(const bf16x8*)&buf[db][c * 8];
            }
#pragma unroll
        for (int m = 0; m < 4; ++m)
#pragma unroll
            for (int n = 0; n < 2; ++n) {
                acc[m][n] = __builtin_amdgcn_mfma_f32_16x16x32_bf16(
                    af[m][0], bfr[n][0], acc[m][n], 0, 0, 0);
                acc[m][n] = __builtin_amdgcn_mfma_f32_16x16x32_bf16(
                    af[m][1], bfr[n][1], acc[m][n], 0, 0, 0);
            }
        __syncthreads();  // drains stage(kt+1); protects buf reuse
        db ^= 1;
    }

    const int col_l = lane & 15, rq = lane >> 4;
#pragma unroll
    for (int m = 0; m < 4; ++m)
#pragma unroll
        for (int n = 0; n < 2; ++n) {
            const int gc = j0 + wid * 32 + n * 16 + col_l;
            const float bias = b1[gc];
#pragma unroll
            for (int q = 0; q < 4; ++q) {
                const int gr = n0 + m * 16 + rq * 4 + q;
                h[(size_t)gr * kHID + gc] = fmaxf(acc[m][n][q] + bias, 0.f);
            }
        }
}

// ---------------------------------------------------------------------------
// Aggregation layer 2: wave per dst node, float4 gather of h rows (1KB,
// 16B-aligned), fp32 mean, no atomics.
// ---------------------------------------------------------------------------
__global__ __launch_bounds__(64)
void aggregate2_kernel(const float* __restrict__ h, const int* __restrict__ off,
                       const int* __restrict__ ebuf, float* __restrict__ agg) {
    const int d = blockIdx.x;
    const int t = threadIdx.x;
    const int b = off[d], e = off[d + 1];
    float ax = 0.f, ay = 0.f, az = 0.f, aw = 0.f;
    int s_next = (b < e) ? ebuf[b] : 0;
    for (int i = b; i < e; ++i) {
        const int s = s_next;
        if (i + 1 < e) s_next = ebuf[i + 1];
        const float4 r = ((const float4*)(h + (size_t)s * kHID))[t];
        ax += r.x; ay += r.y; az += r.z; aw += r.w;
    }
    const float inv = 1.0f / fmaxf((float)(e - b), 1.0f);
    float4 o;
    o.x = ax * inv; o.y = ay * inv; o.z = az * inv; o.w = aw * inv;
    ((float4*)(agg + (size_t)d * kHID))[t] = o;
}

// ---------------------------------------------------------------------------
// Layer 2: logits = agg2m @ W2l + b2 + h[:N0] @ W2r ; row log_softmax.
// One wave per output node; agg2m is already the mean.
// ---------------------------------------------------------------------------
__global__ __launch_bounds__(64)
void layer2_kernel(const float* __restrict__ agg2m, const float* __restrict__ h,
                   const float* __restrict__ W2l, const float* __restrict__ W2r,
                   const float* __restrict__ b2, float* __restrict__ out) {
    __shared__ float sa[kHID];
    __shared__ float sh[kHID];
    const int n = blockIdx.x;
    const int t = threadIdx.x;
    for (int k = t; k < kHID; k += 64) {
        sa[k] = agg2m[(size_t)n * kHID + k];
        sh[k] = h[(size_t)n * kHID + k];
    }
    __syncthreads();

    float logit = 0.0f;
    if (t < kOUT) {
        logit = b2[t];
        for (int k = 0; k < kHID; ++k)
            logit += sa[k] * W2l[k * kOUT + t] + sh[k] * W2r[k * kOUT + t];
    }
    float m = (t < kOUT) ? logit : -INFINITY;
#pragma unroll
    for (int off = 32; off >= 1; off >>= 1)
        m = fmaxf(m, __shfl_xor(m, off));
    float e = (t < kOUT) ? expf(logit - m) : 0.0f;
    float s = e;
#pragma unroll
    for (int off = 32; off >= 1; off >>= 1)
        s += __shfl_xor(s, off);
    if (t < kOUT)
        out[(size_t)n * kOUT + t] = logit - m - logf(s);
}

// ---------------------------------------------------------------------------
extern "C" void kernel_launch(void* const* d_in, const int* in_sizes, int n_in,
                              void* d_out, int out_size, void* d_ws, size_t ws_size,
                              hipStream_t stream) {
    const float* x    = (const float*)d_in[0];
    const int*   src1 = (const int*)d_in[1];
    const int*   dst1 = (const int*)d_in[2];
    const int*   src2 = (const int*)d_in[3];
    const int*   dst2 = (const int*)d_in[4];
    const float* W1l  = (const float*)d_in[5];
    const float* W1r  = (const float*)d_in[6];
    const float* b1   = (const float*)d_in[7];
    const float* W2l  = (const float*)d_in[8];
    const float* W2r  = (const float*)d_in[9];
    const float* b2   = (const float*)d_in[10];
    float* out = (float*)d_out;

    // ---- workspace layout ----
    int* cnt1 = (int*)d_ws;                  // kN1
    int* cur1 = cnt1 + kN1;                  // kN1
    int* cnt2 = cur1 + kN1;                  // kN0
    int* cur2 = cnt2 + kN0;                  // kN0
    int* off1 = cur2 + kN0;                  // kN1 + 1
    int* off2 = off1 + kN1 + 1;              // kN0 + 1
    int* ebuf1 = off2 + kN0 + 1;             // kE1
    int* ebuf2 = ebuf1 + kE1;                // kE2
    size_t int_words = (size_t)2 * kN1 + 2 * kN0 + (kN1 + 1) + (kN0 + 1) + kE1 + kE2;
    int_words = (int_words + 7) & ~(size_t)7;  // 32B align

    ushort* aggb = (ushort*)((int*)d_ws + int_words);   // kN1*kKP bf16
    ushort* xb   = aggb + (size_t)kN1 * kKP;            // kN1*kKP
    ushort* wlt  = xb + (size_t)kN1 * kKP;              // kHID*kKP
    ushort* wrt  = wlt + (size_t)kHID * kKP;            // kHID*kKP
    float* h     = (float*)(wrt + (size_t)kHID * kKP);  // kN1*kHID fp32
    float* agg2m = h + (size_t)kN1 * kHID;              // kN0*kHID fp32

    // zero the histogram/cursor region (cnt1,cur1,cnt2,cur2 are contiguous)
    hipMemsetAsync(cnt1, 0, ((size_t)2 * kN1 + 2 * kN0) * sizeof(int), stream);

    constexpr int EB1 = (kE1 + 255) / 256;
    constexpr int EB2 = (kE2 + 255) / 256;
    hist_kernel<<<EB1, 256, 0, stream>>>(dst1, cnt1, kE1);
    hist_kernel<<<EB2, 256, 0, stream>>>(dst2, cnt2, kE2);
    scan_kernel<<<1, 256, 0, stream>>>(cnt1, off1, kN1);
    scan_kernel<<<1, 256, 0, stream>>>(cnt2, off2, kN0);
    bucket_kernel<<<EB1, 256, 0, stream>>>(src1, dst1, off1, cur1, ebuf1, kE1);
    bucket_kernel<<<EB2, 256, 0, stream>>>(src2, dst2, off2, cur2, ebuf2, kE2);

    conv_x1_kernel<<<(kN1 * 304) / 256, 256, 0, stream>>>(x, xb);
    conv_w_kernel<<<kHID, 256, 0, stream>>>(W1l, wlt);
    conv_w_kernel<<<kHID, 256, 0, stream>>>(W1r, wrt);

    aggregate1_kernel<<<kN1, 128, 0, stream>>>(x, off1, ebuf1, aggb);

    layer1_mfma<<<(kN1 / 64) * 2, 256, 0, stream>>>(aggb, xb, wlt, wrt, b1, h);

    aggregate2_kernel<<<kN0, 64, 0, stream>>>(h, off2, ebuf2, agg2m);
    layer2_kernel<<<kN0, 64, 0, stream>>>(agg2m, h, W2l, W2r, b2, out);
}

// Round 5
// 247.496 us; speedup vs baseline: 1.0447x; 1.0447x over previous
//
#include <hip/hip_runtime.h>
#include <hip/hip_bf16.h>
#include <math.h>

// Problem constants (from reference)
constexpr int kN2 = 180224, kN1 = 11264, kN0 = 1024;
constexpr int kE1 = 168960, kE2 = 10240;
constexpr int kIN = 602, kHID = 256, kOUT = 41;
constexpr int kKP = 608;  // kIN padded to multiple of 32 (MFMA K)

typedef __attribute__((ext_vector_type(8))) short bf16x8;
typedef __attribute__((ext_vector_type(4))) float f32x4;

static __device__ __forceinline__ ushort f2bf(float v) {
    return __bfloat16_as_ushort(__float2bfloat16(v));
}

// ---------------------------------------------------------------------------
// CSR build, both edge lists in one launch each: histogram -> scan -> bucket.
// ---------------------------------------------------------------------------
__global__ __launch_bounds__(256)
void hist_both_kernel(const int* __restrict__ dst1, const int* __restrict__ dst2,
                      int* __restrict__ cnt1, int* __restrict__ cnt2) {
    const int gid = blockIdx.x * 256 + threadIdx.x;
    if (gid < kE1) {
        atomicAdd(&cnt1[dst1[gid]], 1);
    } else if (gid < kE1 + kE2) {
        atomicAdd(&cnt2[dst2[gid - kE1]], 1);
    }
}

// block 0 scans cnt1[kN1] -> off1; block 1 scans cnt2[kN0] -> off2
__global__ __launch_bounds__(256)
void scan_both_kernel(const int* __restrict__ cnt1, int* __restrict__ off1,
                      const int* __restrict__ cnt2, int* __restrict__ off2) {
    __shared__ int part[256];
    const int t = threadIdx.x;
    const int* cnt = blockIdx.x ? cnt2 : cnt1;
    int* off = blockIdx.x ? off2 : off1;
    const int nN = blockIdx.x ? kN0 : kN1;
    const int CH = nN >> 8;
    const int base = t * CH;
    int s = 0;
    for (int i = 0; i < CH; ++i) s += cnt[base + i];
    part[t] = s;
    __syncthreads();
    for (int ofs = 1; ofs < 256; ofs <<= 1) {
        int v = (t >= ofs) ? part[t - ofs] : 0;
        __syncthreads();
        if (t >= ofs) part[t] += v;
        __syncthreads();
    }
    int run = (t == 0) ? 0 : part[t - 1];
    for (int i = 0; i < CH; ++i) {
        off[base + i] = run;
        run += cnt[base + i];
    }
    if (t == 255) off[nN] = run;
}

__global__ __launch_bounds__(256)
void bucket_both_kernel(const int* __restrict__ src1, const int* __restrict__ dst1,
                        const int* __restrict__ off1, int* __restrict__ cur1,
                        int* __restrict__ ebuf1,
                        const int* __restrict__ src2, const int* __restrict__ dst2,
                        const int* __restrict__ off2, int* __restrict__ cur2,
                        int* __restrict__ ebuf2) {
    const int gid = blockIdx.x * 256 + threadIdx.x;
    if (gid < kE1) {
        const int d = dst1[gid];
        const int p = atomicAdd(&cur1[d], 1);
        ebuf1[off1[d] + p] = src1[gid];
    } else if (gid < kE1 + kE2) {
        const int e = gid - kE1;
        const int d = dst2[e];
        const int p = atomicAdd(&cur2[d], 1);
        ebuf2[off2[d] + p] = src2[e];
    }
}

// ---------------------------------------------------------------------------
// Aggregation layer 1: block per dst node, float2 loads, 2-edge unroll for
// doubled memory-level parallelism, fp32 accumulate, packed bf16 mean store
// into the padded [kN1][608] GEMM operand buffer.
// ---------------------------------------------------------------------------
__global__ __launch_bounds__(128)
void aggregate1_kernel(const float* __restrict__ x, const int* __restrict__ off,
                       const int* __restrict__ ebuf, ushort* __restrict__ aggb) {
    const int d = blockIdx.x;
    const int t = threadIdx.x;
    const int b = off[d], e = off[d + 1];
    float p0x = 0.f, p0y = 0.f, p1x = 0.f, p1y = 0.f, p2x = 0.f, p2y = 0.f;
    float q0x = 0.f, q0y = 0.f, q1x = 0.f, q1y = 0.f, q2x = 0.f, q2y = 0.f;
    int i = b;
    for (; i + 2 <= e; i += 2) {
        const int s0 = ebuf[i], s1 = ebuf[i + 1];
        const float2* r0 = (const float2*)(x + (size_t)s0 * kIN);
        const float2* r1 = (const float2*)(x + (size_t)s1 * kIN);
        const float2 a0 = r0[t], a1 = r0[t + 128];
        const float2 b0 = r1[t], b1 = r1[t + 128];
        p0x += a0.x; p0y += a0.y; p1x += a1.x; p1y += a1.y;
        q0x += b0.x; q0y += b0.y; q1x += b1.x; q1y += b1.y;
        if (t < 45) {
            const float2 a2 = r0[t + 256], b2 = r1[t + 256];
            p2x += a2.x; p2y += a2.y; q2x += b2.x; q2y += b2.y;
        }
    }
    if (i < e) {
        const int s0 = ebuf[i];
        const float2* r0 = (const float2*)(x + (size_t)s0 * kIN);
        const float2 a0 = r0[t], a1 = r0[t + 128];
        p0x += a0.x; p0y += a0.y; p1x += a1.x; p1y += a1.y;
        if (t < 45) {
            const float2 a2 = r0[t + 256];
            p2x += a2.x; p2y += a2.y;
        }
    }
    p0x += q0x; p0y += q0y; p1x += q1x; p1y += q1y; p2x += q2x; p2y += q2y;
    const float inv = 1.0f / fmaxf((float)(e - b), 1.0f);
    uint* ar = (uint*)(aggb + (size_t)d * kKP);  // 304 uints per row
    ar[t]       = (uint)f2bf(p0x * inv) | ((uint)f2bf(p0y * inv) << 16);
    ar[t + 128] = (uint)f2bf(p1x * inv) | ((uint)f2bf(p1y * inv) << 16);
    if (t < 45) ar[t + 256] = (uint)f2bf(p2x * inv) | ((uint)f2bf(p2y * inv) << 16);
    if (t >= 45 && t < 48) ar[t + 256] = 0u;  // zero pad shorts 602..607
}

// ---------------------------------------------------------------------------
// Convert x[:N1] fp32 [kN1][602] -> bf16 [kN1][608]; flat uint-task grid.
// ---------------------------------------------------------------------------
__global__ __launch_bounds__(256)
void conv_x1_kernel(const float* __restrict__ x, ushort* __restrict__ xb) {
    const int task = blockIdx.x * 256 + threadIdx.x;  // row*304 + u
    const int row = task / 304;
    const int u = task - row * 304;
    uint v = 0u;
    if (u < 301) {
        const float2 f = *(const float2*)(x + (size_t)row * kIN + 2 * u);
        v = (uint)f2bf(f.x) | ((uint)f2bf(f.y) << 16);
    }
    ((uint*)xb)[task] = v;
}

// Convert+transpose both W1 [602][256] -> Wt bf16 [256][608]; grid 512.
__global__ __launch_bounds__(256)
void conv_w_both_kernel(const float* __restrict__ W1l, const float* __restrict__ W1r,
                        ushort* __restrict__ wlt, ushort* __restrict__ wrt) {
    const int which = blockIdx.x >> 8;
    const int j = blockIdx.x & 255;
    const float* W = which ? W1r : W1l;
    ushort* Wt = which ? wrt : wlt;
    for (int k = threadIdx.x; k < kKP; k += 256) {
        float v = (k < kIN) ? W[(size_t)k * kHID + j] : 0.f;
        Wt[(size_t)j * kKP + k] = f2bf(v);
    }
}

// ---------------------------------------------------------------------------
// Layer-1 GEMM via MFMA: h = relu(agg @ W1l + b1 + x @ W1r).
// 32x128 block tile (704 blocks = 2.75/CU for cross-block latency hiding),
// 4 waves each owning 32x32, K-step 32, double-buffered 40KB LDS staged by
// global_load_lds width=16. Linear LDS dest + inverse-swizzled SOURCE +
// swizzled READ (rule #21); slot = k8 ^ ((row>>1)&3) -> frag ds_read_b128
// is 2-way (free, m136). One __syncthreads per K-step.
// ---------------------------------------------------------------------------
constexpr int kNT = kKP / 32;  // 19 K-steps

__global__ __launch_bounds__(256)
void layer1_mfma(const ushort* __restrict__ aggb, const ushort* __restrict__ xb,
                 const ushort* __restrict__ wlt, const ushort* __restrict__ wrt,
                 const float* __restrict__ b1, float* __restrict__ h) {
    __shared__ ushort buf[2][1280 * 8];  // 2 x 20KB
    const int t = threadIdx.x;
    const int lane = t & 63, wid = t >> 6;
    const int bid = blockIdx.x;
    const int n0 = (bid >> 1) * 32;
    const int j0 = (bid & 1) * 128;

    f32x4 acc[2][2];
#pragma unroll
    for (int m = 0; m < 2; ++m)
#pragma unroll
        for (int n = 0; n < 2; ++n) acc[m][n] = (f32x4){0.f, 0.f, 0.f, 0.f};

    // stage K-step kt into buf[db]: 1280 16B chunks = 20 wave-stripes of 64
    auto stage = [&](int kt, int db) {
        const int k0 = kt * 32;
#pragma unroll
        for (int i = 0; i < 5; ++i) {
            const int stripe = i * 4 + wid;
            const int c = stripe * 64 + lane;
            const ushort* g;
            if (c < 256) {  // A: mat(1b) x row(5b) x slot(2b)
                const int mat = c >> 7, r = (c >> 2) & 31, slot = c & 3;
                const int k8 = slot ^ ((r >> 1) & 3);
                g = (mat ? xb : aggb) + (size_t)(n0 + r) * kKP + k0 + k8 * 8;
            } else {        // B: mat(1b) x row(7b) x slot(2b)
                const int c2 = c - 256;
                const int mat = c2 >> 9, rb = (c2 >> 2) & 127, slot = c2 & 3;
                const int k8 = slot ^ ((rb >> 1) & 3);
                g = (mat ? wrt : wlt) + (size_t)(j0 + rb) * kKP + k0 + k8 * 8;
            }
            __builtin_amdgcn_global_load_lds(
                (const __attribute__((address_space(1))) void*)g,
                (__attribute__((address_space(3))) void*)&buf[db][stripe * 512],
                16, 0, 0);
        }
    };

    stage(0, 0);
    __syncthreads();

    const int rl = lane & 15;
    const int k8r = lane >> 4;
    int db = 0;
    for (int kt = 0; kt < kNT; ++kt) {
        if (kt + 1 < kNT) stage(kt + 1, db ^ 1);

        bf16x8 af[2][2], bfr[2][2];
#pragma unroll
        for (int m = 0; m < 2; ++m)
#pragma unroll
            for (int p = 0; p < 2; ++p) {
                const int r = m * 16 + rl;
                const int slot = k8r ^ ((r >> 1) & 3);
                const int c = p * 128 + r * 4 + slot;
                af[m][p] = *(const bf16x8*)&buf[db][c * 8];
            }
#pragma unroll
        for (int n = 0; n < 2; ++n)
#pragma unroll
            for (int p = 0; p < 2; ++p) {
                const int rb = wid * 32 + n * 16 + rl;
                const int slot = k8r ^ ((rb >> 1) & 3);
                const int c = 256 + p * 512 + rb * 4 + slot;
                bfr[n][p] = *(const bf16x8*)&buf[db][c * 8];
            }
#pragma unroll
        for (int m = 0; m < 2; ++m)
#pragma unroll
            for (int n = 0; n < 2; ++n) {
                acc[m][n] = __builtin_amdgcn_mfma_f32_16x16x32_bf16(
                    af[m][0], bfr[n][0], acc[m][n], 0, 0, 0);
                acc[m][n] = __builtin_amdgcn_mfma_f32_16x16x32_bf16(
                    af[m][1], bfr[n][1], acc[m][n], 0, 0, 0);
            }
        __syncthreads();  // drains stage(kt+1); protects buf reuse
        db ^= 1;
    }

    const int col_l = lane & 15, rq = lane >> 4;
#pragma unroll
    for (int m = 0; m < 2; ++m)
#pragma unroll
        for (int n = 0; n < 2; ++n) {
            const int gc = j0 + wid * 32 + n * 16 + col_l;
            const float bias = b1[gc];
#pragma unroll
            for (int q = 0; q < 4; ++q) {
                const int gr = n0 + m * 16 + rq * 4 + q;
                h[(size_t)gr * kHID + gc] = fmaxf(acc[m][n][q] + bias, 0.f);
            }
        }
}

// ---------------------------------------------------------------------------
// Layer 2 fused: gather-mean h[src2] rows (CSR, no atomics) + GEMV + row
// log_softmax. One wave per output node.
// ---------------------------------------------------------------------------
__global__ __launch_bounds__(64)
void layer2_fused(const float* __restrict__ h, const int* __restrict__ off,
                  const int* __restrict__ ebuf, const float* __restrict__ W2l,
                  const float* __restrict__ W2r, const float* __restrict__ b2,
                  float* __restrict__ out) {
    __shared__ float sa[kHID];
    __shared__ float sh[kHID];
    const int n = blockIdx.x;
    const int t = threadIdx.x;
    const int b = off[n], e = off[n + 1];
    float ax = 0.f, ay = 0.f, az = 0.f, aw = 0.f;
    for (int i = b; i < e; ++i) {
        const float4 r = ((const float4*)(h + (size_t)ebuf[i] * kHID))[t];
        ax += r.x; ay += r.y; az += r.z; aw += r.w;
    }
    const float inv = 1.0f / fmaxf((float)(e - b), 1.0f);
    float4 o;
    o.x = ax * inv; o.y = ay * inv; o.z = az * inv; o.w = aw * inv;
    ((float4*)sa)[t] = o;
    ((float4*)sh)[t] = ((const float4*)(h + (size_t)n * kHID))[t];
    __syncthreads();

    float logit = 0.0f;
    if (t < kOUT) {
        logit = b2[t];
        for (int k = 0; k < kHID; ++k)
            logit += sa[k] * W2l[k * kOUT + t] + sh[k] * W2r[k * kOUT + t];
    }
    float m = (t < kOUT) ? logit : -INFINITY;
#pragma unroll
    for (int ofs = 32; ofs >= 1; ofs >>= 1)
        m = fmaxf(m, __shfl_xor(m, ofs));
    float ev = (t < kOUT) ? expf(logit - m) : 0.0f;
    float s = ev;
#pragma unroll
    for (int ofs = 32; ofs >= 1; ofs >>= 1)
        s += __shfl_xor(s, ofs);
    if (t < kOUT)
        out[(size_t)n * kOUT + t] = logit - m - logf(s);
}

// ---------------------------------------------------------------------------
extern "C" void kernel_launch(void* const* d_in, const int* in_sizes, int n_in,
                              void* d_out, int out_size, void* d_ws, size_t ws_size,
                              hipStream_t stream) {
    const float* x    = (const float*)d_in[0];
    const int*   src1 = (const int*)d_in[1];
    const int*   dst1 = (const int*)d_in[2];
    const int*   src2 = (const int*)d_in[3];
    const int*   dst2 = (const int*)d_in[4];
    const float* W1l  = (const float*)d_in[5];
    const float* W1r  = (const float*)d_in[6];
    const float* b1   = (const float*)d_in[7];
    const float* W2l  = (const float*)d_in[8];
    const float* W2r  = (const float*)d_in[9];
    const float* b2   = (const float*)d_in[10];
    float* out = (float*)d_out;

    // ---- workspace layout ----
    int* cnt1 = (int*)d_ws;                  // kN1
    int* cur1 = cnt1 + kN1;                  // kN1
    int* cnt2 = cur1 + kN1;                  // kN0
    int* cur2 = cnt2 + kN0;                  // kN0
    int* off1 = cur2 + kN0;                  // kN1 + 1
    int* off2 = off1 + kN1 + 1;              // kN0 + 1
    int* ebuf1 = off2 + kN0 + 1;             // kE1
    int* ebuf2 = ebuf1 + kE1;                // kE2
    size_t int_words = (size_t)2 * kN1 + 2 * kN0 + (kN1 + 1) + (kN0 + 1) + kE1 + kE2;
    int_words = (int_words + 7) & ~(size_t)7;  // 32B align

    ushort* aggb = (ushort*)((int*)d_ws + int_words);   // kN1*kKP bf16
    ushort* xb   = aggb + (size_t)kN1 * kKP;            // kN1*kKP
    ushort* wlt  = xb + (size_t)kN1 * kKP;              // kHID*kKP
    ushort* wrt  = wlt + (size_t)kHID * kKP;            // kHID*kKP
    float* h     = (float*)(wrt + (size_t)kHID * kKP);  // kN1*kHID fp32

    // zero histogram/cursor region (cnt1,cur1,cnt2,cur2 contiguous)
    hipMemsetAsync(cnt1, 0, ((size_t)2 * kN1 + 2 * kN0) * sizeof(int), stream);

    constexpr int EB = (kE1 + kE2 + 255) / 256;  // 700
    hist_both_kernel<<<EB, 256, 0, stream>>>(dst1, dst2, cnt1, cnt2);
    scan_both_kernel<<<2, 256, 0, stream>>>(cnt1, off1, cnt2, off2);
    bucket_both_kernel<<<EB, 256, 0, stream>>>(src1, dst1, off1, cur1, ebuf1,
                                               src2, dst2, off2, cur2, ebuf2);

    conv_x1_kernel<<<(kN1 * 304) / 256, 256, 0, stream>>>(x, xb);
    conv_w_both_kernel<<<512, 256, 0, stream>>>(W1l, W1r, wlt, wrt);

    aggregate1_kernel<<<kN1, 128, 0, stream>>>(x, off1, ebuf1, aggb);

    layer1_mfma<<<(kN1 / 32) * 2, 256, 0, stream>>>(aggb, xb, wlt, wrt, b1, h);

    layer2_fused<<<kN0, 64, 0, stream>>>(h, off2, ebuf2, W2l, W2r, b2, out);
}